// Round 16
// baseline (182.059 us; speedup 1.0000x reference)
//
#include <hip/hip_runtime.h>
#include <stdint.h>
#include <string.h>
#include <math.h>

typedef float f32x4 __attribute__((ext_vector_type(4)));
typedef unsigned int u32;

#define DD 128

__device__ __forceinline__ float fsilu(float x) {
    float e = __expf(-x);
    return x * __builtin_amdgcn_rcpf(1.0f + e);
}
// pack 4 floats -> 4 fp8 e4m3 (OCP) in one u32
__device__ __forceinline__ u32 pk4fp8(float a, float b, float c, float d) {
    u32 r = __builtin_amdgcn_cvt_pk_fp8_f32(a, b, 0u, false);
    return __builtin_amdgcn_cvt_pk_fp8_f32(c, d, r, true);
}

// ---- decode, self-filling (validated R14/R15): touched cells hold packed
// >= 0xE0000000 (atomicMax re-promotes every replay; all entry states --
// memset 0x00, poison 0xAA, decoded floats <= 0xC1B84F3B -- are smaller).
// Untouched cells get log(1e-10) bits written only if absent.
__device__ __forceinline__ float decz(u32 u) {
    float z = (float)(int)(u & 0x3FFFu) * (1.0f / 256.0f) - 40.0f;
    float s = __builtin_amdgcn_rcpf(1.0f + __expf(-z));
    return __logf(s + 1e-10f);
}
__global__ void decode_sparse(u32* __restrict__ p, long n4, u32 le) {
    long i  = (long)blockIdx.x * blockDim.x + threadIdx.x;
    long st = (long)gridDim.x * blockDim.x;
    for (long k = i; k < n4; k += st) {
        uint4 u = ((const uint4*)p)[k];
        float* f = (float*)(p + k * 4);
        if (u.x >= 0xE0000000u) f[0] = decz(u.x); else if (u.x != le) ((u32*)f)[0] = le;
        if (u.y >= 0xE0000000u) f[1] = decz(u.y); else if (u.y != le) ((u32*)f)[1] = le;
        if (u.z >= 0xE0000000u) f[2] = decz(u.z); else if (u.z != le) ((u32*)f)[2] = le;
        if (u.w >= 0xE0000000u) f[3] = decz(u.w); else if (u.w != le) ((u32*)f)[3] = le;
    }
}

// OCCUPANCY lever on the R15 fp8 chassis: block 512 thr = 8 indep waves,
// LDS 50.7 KB/block -> 3 blocks/CU (152 KB), 24 waves/CU = 6 waves/SIMD
// (+50% TLP over R15's 4) PROVIDED VGPR <= 85. Register diet: no prefetch
// buffer (neutral, R10-vs-R8), edge load+convert in two 16-reg halves,
// single acc[] reused for both layers. All math identical to R15
// (fp8 frag-major W, per-wave Hs, absmax 0.0547 validated).
__global__ __launch_bounds__(512)
void mlp_scatter(const float* __restrict__ A,
                 const int* __restrict__ eidx,
                 const float* __restrict__ W1, const float* __restrict__ B1,
                 const float* __restrict__ W2, const float* __restrict__ B2,
                 const float* __restrict__ WO, const float* __restrict__ BO,
                 u32* __restrict__ out,
                 int E, int nWT, int N)
{
    extern __shared__ char smem[];
    uint2* W1s = (uint2*)smem;                    // [8][4][64] 16 KB
    uint2* W2s = (uint2*)(smem + 16384);          // 16 KB
    float* b1s = (float*)(smem + 32768);
    float* b2s = (float*)(smem + 33280);
    float* wos = (float*)(smem + 33792);
    uint2* Hs  = (uint2*)(smem + 34304);          // [8][4][64] 16 KB

    const int tid  = threadIdx.x;
    const int lane = tid & 63;
    const int wave = tid >> 6;
    const int lrow = lane & 15;
    const int lg   = lane >> 4;

    // ---- stage W1/W2 fp32 -> fp8 frag-major LDS (one-time, validated) ----
    #pragma unroll
    for (int c = 0; c < 4; ++c) {
        int id = c * 512 + tid;                   // 2048 slots
        int mt = id >> 8, kk = (id >> 6) & 3, ln = id & 63;
        const float* p1 = W1 + (mt * 16 + (ln & 15)) * DD + kk * 32 + (ln >> 4) * 8;
        const float* p2 = W2 + (mt * 16 + (ln & 15)) * DD + kk * 32 + (ln >> 4) * 8;
        float4 x0 = *(const float4*)p1, x1 = *(const float4*)(p1 + 4);
        float4 y0 = *(const float4*)p2, y1 = *(const float4*)(p2 + 4);
        W1s[mt * 256 + kk * 64 + ln] = make_uint2(pk4fp8(x0.x, x0.y, x0.z, x0.w),
                                                  pk4fp8(x1.x, x1.y, x1.z, x1.w));
        W2s[mt * 256 + kk * 64 + ln] = make_uint2(pk4fp8(y0.x, y0.y, y0.z, y0.w),
                                                  pk4fp8(y1.x, y1.y, y1.z, y1.w));
    }
    if (tid < DD) { b1s[tid] = B1[tid]; b2s[tid] = B2[tid]; wos[tid] = WO[tid]; }
    const float bo = BO[0];
    const size_t NN = (size_t)N * (size_t)N;
    uint2* HsW = Hs + wave * 256;                 // [4][64] per wave
    __syncthreads();   // the ONLY barrier

    const int wid  = blockIdx.x * 8 + wave;
    const int step = (int)gridDim.x * 8;

    for (int wt = wid; wt < nWT; wt += step) {
        const int r0  = wt << 4;              // global edge-row base
        const int b   = r0 / E;               // wave-uniform (E % 16 == 0)
        const int ei0 = r0 - b * E;
        int i0 = 0, j0 = 0;
        if (lane < 16) {
            i0 = eidx[(size_t)(2 * b) * E + ei0 + lane];
            j0 = eidx[(size_t)(2 * b + 1) * E + ei0 + lane];
        }

        // ---- load+convert this tile in two halves (peak 16 f32 regs) ----
        uint2 ef[4];
        {
            const float* Ar = A + (size_t)(r0 + lrow) * DD + lg * 8;
            float4 h0 = *(const float4*)(Ar);
            float4 h1 = *(const float4*)(Ar + 4);
            float4 h2 = *(const float4*)(Ar + 32);
            float4 h3 = *(const float4*)(Ar + 36);
            ef[0] = make_uint2(pk4fp8(h0.x, h0.y, h0.z, h0.w),
                               pk4fp8(h1.x, h1.y, h1.z, h1.w));
            ef[1] = make_uint2(pk4fp8(h2.x, h2.y, h2.z, h2.w),
                               pk4fp8(h3.x, h3.y, h3.z, h3.w));
            h0 = *(const float4*)(Ar + 64);
            h1 = *(const float4*)(Ar + 68);
            h2 = *(const float4*)(Ar + 96);
            h3 = *(const float4*)(Ar + 100);
            ef[2] = make_uint2(pk4fp8(h0.x, h0.y, h0.z, h0.w),
                               pk4fp8(h1.x, h1.y, h1.z, h1.w));
            ef[3] = make_uint2(pk4fp8(h2.x, h2.y, h2.z, h2.w),
                               pk4fp8(h3.x, h3.y, h3.z, h3.w));
        }

        // ---- layer 1: C1[f][e], acc init = b1 ----
        f32x4 acc[8];
        #pragma unroll
        for (int mt = 0; mt < 8; ++mt)
            acc[mt] = *(const f32x4*)&b1s[mt * 16 + lg * 4];
        #pragma unroll
        for (int kk = 0; kk < 4; ++kk)
            #pragma unroll
            for (int mt = 0; mt < 8; ++mt)
                acc[mt] = __builtin_amdgcn_mfma_f32_16x16x32_fp8_fp8(
                    __builtin_bit_cast(long, W1s[mt * 256 + kk * 64 + lane]),
                    __builtin_bit_cast(long, ef[kk]), acc[mt], 0, 0, 0);

        // ---- silu -> fp8 -> Hs (frag-major writer algebra, validated) ----
        #pragma unroll
        for (int mt = 0; mt < 8; ++mt) {
            int lnp = (((mt & 1) << 1) | (lg >> 1)) * 16 + lrow;
            u32 pw = pk4fp8(fsilu(acc[mt][0]), fsilu(acc[mt][1]),
                            fsilu(acc[mt][2]), fsilu(acc[mt][3]));
            ((u32*)&HsW[(mt >> 1) * 64 + lnp])[lg & 1] = pw;
        }

        // ---- layer 2: reuse acc[], init = b2 (same-wave Hs b64 reads) ----
        #pragma unroll
        for (int mt = 0; mt < 8; ++mt)
            acc[mt] = *(const f32x4*)&b2s[mt * 16 + lg * 4];
        #pragma unroll
        for (int kk = 0; kk < 4; ++kk) {
            long hf = __builtin_bit_cast(long, HsW[kk * 64 + lane]);
            #pragma unroll
            for (int mt = 0; mt < 8; ++mt)
                acc[mt] = __builtin_amdgcn_mfma_f32_16x16x32_fp8_fp8(
                    __builtin_bit_cast(long, W2s[mt * 256 + kk * 64 + lane]),
                    hf, acc[mt], 0, 0, 0);
        }

        // ---- z = wo . silu(acc): per-lane partial, reduce over lane-groups ----
        float zp = 0.f;
        #pragma unroll
        for (int mt = 0; mt < 8; ++mt) {
            f32x4 w4 = *(const f32x4*)&wos[mt * 16 + lg * 4];
            zp += w4[0] * fsilu(acc[mt][0]) + w4[1] * fsilu(acc[mt][1])
                + w4[2] * fsilu(acc[mt][2]) + w4[3] * fsilu(acc[mt][3]);
        }
        zp += __shfl_xor(zp, 16);
        zp += __shfl_xor(zp, 32);

        // ---- scatter: 16 lanes, atomicMax packed (fire-and-forget) ----
        if (lane < 16) {
            float z = zp + bo;
            int qz = (int)((z + 40.0f) * 256.0f + 0.5f);
            qz = qz < 0 ? 0 : (qz > 16383 ? 16383 : qz);
            u32 packed = 0xE0000000u | ((u32)(ei0 + lane + 1) << 14) | (u32)qz;
            atomicMax(&out[(size_t)b * NN + (size_t)i0 * N + (size_t)j0], packed);
        }
    }
}

extern "C" void kernel_launch(void* const* d_in, const int* in_sizes, int n_in,
                              void* d_out, int out_size, void* d_ws, size_t ws_size,
                              hipStream_t stream) {
    const float* edge_attr  = (const float*)d_in[0];
    const int*   edge_index = (const int*)d_in[1];
    const float* W1   = (const float*)d_in[2];
    const float* b1   = (const float*)d_in[3];
    const float* W2   = (const float*)d_in[4];
    const float* b2   = (const float*)d_in[5];
    const float* Wout = (const float*)d_in[6];
    const float* bout = (const float*)d_in[7];

    long rows = (long)in_sizes[0] / DD;        // B*E = 1,024,000
    int  E    = in_sizes[1] / 64;              // 32000 (B=32)
    int  nWT  = (int)(rows / 16);              // 64000 wave-tiles
    int  Bb   = (int)(rows / E);               // 32
    int  N    = (int)(sqrtf((float)(out_size / Bb)) + 0.5f);   // 1000

    u32* outp = (u32*)d_out;
    long n4 = (long)out_size >> 2;

    float fv = logf(1e-10f);
    u32 LE; memcpy(&LE, &fv, 4);               // log(1e-10) bits, < 0xE0000000

    const int SMEM = 50688;                    // 16K+16K+1.5K+16K + pad
    hipFuncSetAttribute((const void*)mlp_scatter,
                        hipFuncAttributeMaxDynamicSharedMemorySize, SMEM);

    mlp_scatter<<<768, 512, SMEM, stream>>>(edge_attr, edge_index, W1, b1, W2, b2,
                                            Wout, bout, outp, E, nWT, N);
    decode_sparse<<<2048, 256, 0, stream>>>(outp, n4, LE);
}

// Round 17
// 179.497 us; speedup vs baseline: 1.0143x; 1.0143x over previous
//
#include <hip/hip_runtime.h>
#include <stdint.h>
#include <string.h>
#include <math.h>

typedef float f32x4 __attribute__((ext_vector_type(4)));
typedef unsigned int u32;

#define DD 128

__device__ __forceinline__ float fsilu(float x) {
    float e = __expf(-x);
    return x * __builtin_amdgcn_rcpf(1.0f + e);
}
// pack 4 floats -> 4 fp8 e4m3 (OCP) in one u32
__device__ __forceinline__ u32 pk4fp8(float a, float b, float c, float d) {
    u32 r = __builtin_amdgcn_cvt_pk_fp8_f32(a, b, 0u, false);
    return __builtin_amdgcn_cvt_pk_fp8_f32(c, d, r, true);
}

// ---- decode, self-filling (validated R14/R15): touched cells hold packed
// >= 0xE0000000 (atomicMax re-promotes every replay; all entry states --
// memset 0x00, poison 0xAA, decoded floats <= 0xC1B84F3B -- are smaller).
// Untouched cells get log(1e-10) bits written only if absent.
__device__ __forceinline__ float decz(u32 u) {
    float z = (float)(int)(u & 0x3FFFu) * (1.0f / 256.0f) - 40.0f;
    float s = __builtin_amdgcn_rcpf(1.0f + __expf(-z));
    return __logf(s + 1e-10f);
}
__global__ void decode_sparse(u32* __restrict__ p, long n4, u32 le) {
    long i  = (long)blockIdx.x * blockDim.x + threadIdx.x;
    long st = (long)gridDim.x * blockDim.x;
    for (long k = i; k < n4; k += st) {
        uint4 u = ((const uint4*)p)[k];
        float* f = (float*)(p + k * 4);
        if (u.x >= 0xE0000000u) f[0] = decz(u.x); else if (u.x != le) ((u32*)f)[0] = le;
        if (u.y >= 0xE0000000u) f[1] = decz(u.y); else if (u.y != le) ((u32*)f)[1] = le;
        if (u.z >= 0xE0000000u) f[2] = decz(u.z); else if (u.z != le) ((u32*)f)[2] = le;
        if (u.w >= 0xE0000000u) f[3] = decz(u.w); else if (u.w != le) ((u32*)f)[3] = le;
    }
}

// R15 (session best, 179.7 us): R8/R14 chassis, fp8 storage dtype.
// Block = 1024 thr = 16 indep waves, 4 w/SIMD, LDS ~66 KB, one barrier.
// W?s fp8 frag-major uint2[8][4][64] -> ds_read_b64; per-wave Hs 2 KB.
// NE=16, next-tile register prefetch. absmax 0.0547 (fp8, validated).
__global__ __launch_bounds__(1024)
void mlp_scatter(const float* __restrict__ A,
                 const int* __restrict__ eidx,
                 const float* __restrict__ W1, const float* __restrict__ B1,
                 const float* __restrict__ W2, const float* __restrict__ B2,
                 const float* __restrict__ WO, const float* __restrict__ BO,
                 u32* __restrict__ out,
                 int E, int nWT, int N)
{
    extern __shared__ char smem[];
    uint2* W1s = (uint2*)smem;                    // [8][4][64] 16 KB
    uint2* W2s = (uint2*)(smem + 16384);          // 16 KB
    float* b1s = (float*)(smem + 32768);
    float* b2s = (float*)(smem + 33280);
    float* wos = (float*)(smem + 33792);
    uint2* Hs  = (uint2*)(smem + 34304);          // [16][4][64] 32 KB

    const int tid  = threadIdx.x;
    const int lane = tid & 63;
    const int wave = tid >> 6;
    const int lrow = lane & 15;
    const int lg   = lane >> 4;

    // ---- stage W1/W2 fp32 -> fp8 frag-major LDS (one-time, validated R9/R11) ----
    #pragma unroll
    for (int c = 0; c < 2; ++c) {
        int id = c * 1024 + tid;                  // 2048 slots
        int mt = id >> 8, kk = (id >> 6) & 3, ln = id & 63;
        const float* p1 = W1 + (mt * 16 + (ln & 15)) * DD + kk * 32 + (ln >> 4) * 8;
        const float* p2 = W2 + (mt * 16 + (ln & 15)) * DD + kk * 32 + (ln >> 4) * 8;
        float4 x0 = *(const float4*)p1, x1 = *(const float4*)(p1 + 4);
        float4 y0 = *(const float4*)p2, y1 = *(const float4*)(p2 + 4);
        W1s[mt * 256 + kk * 64 + ln] = make_uint2(pk4fp8(x0.x, x0.y, x0.z, x0.w),
                                                  pk4fp8(x1.x, x1.y, x1.z, x1.w));
        W2s[mt * 256 + kk * 64 + ln] = make_uint2(pk4fp8(y0.x, y0.y, y0.z, y0.w),
                                                  pk4fp8(y1.x, y1.y, y1.z, y1.w));
    }
    if (tid < DD) { b1s[tid] = B1[tid]; b2s[tid] = B2[tid]; wos[tid] = WO[tid]; }
    const float bo = BO[0];
    const size_t NN = (size_t)N * (size_t)N;
    uint2* HsW = Hs + wave * 256;                 // [4][64] per wave
    __syncthreads();   // the ONLY barrier

    const int wid  = blockIdx.x * 16 + wave;
    const int step = (int)gridDim.x * 16;
    if (wid >= nWT) return;

    // ---- prologue: load first tile's edge rows into va ----
    float4 va[8];
    {
        const float* Ar = A + (size_t)((wid << 4) + lrow) * DD;
        #pragma unroll
        for (int kk = 0; kk < 4; ++kk) {
            const float* p = Ar + kk * 32 + lg * 8;
            va[2 * kk]     = *(const float4*)p;
            va[2 * kk + 1] = *(const float4*)(p + 4);
        }
    }

    for (int wt = wid; wt < nWT; wt += step) {
        const int r0  = wt << 4;              // global edge-row base
        const int b   = r0 / E;               // wave-uniform (E % 16 == 0)
        const int ei0 = r0 - b * E;
        int i0 = 0, j0 = 0;
        if (lane < 16) {
            i0 = eidx[(size_t)(2 * b) * E + ei0 + lane];
            j0 = eidx[(size_t)(2 * b + 1) * E + ei0 + lane];
        }

        // ---- convert current tile to fp8 B-frags (va becomes dead) ----
        uint2 ef[4];
        #pragma unroll
        for (int kk = 0; kk < 4; ++kk)
            ef[kk] = make_uint2(
                pk4fp8(va[2*kk].x,   va[2*kk].y,   va[2*kk].z,   va[2*kk].w),
                pk4fp8(va[2*kk+1].x, va[2*kk+1].y, va[2*kk+1].z, va[2*kk+1].w));

        // ---- PREFETCH next tile's rows into va (completes under MFMA) ----
        {
            int tn = wt + step; if (tn >= nWT) tn = wt;
            const float* Ar = A + (size_t)((tn << 4) + lrow) * DD;
            #pragma unroll
            for (int kk = 0; kk < 4; ++kk) {
                const float* p = Ar + kk * 32 + lg * 8;
                va[2 * kk]     = *(const float4*)p;
                va[2 * kk + 1] = *(const float4*)(p + 4);
            }
        }

        // ---- layer 1: C1[f][e], acc init = b1 ----
        f32x4 acc[8];
        #pragma unroll
        for (int mt = 0; mt < 8; ++mt)
            acc[mt] = *(const f32x4*)&b1s[mt * 16 + lg * 4];
        #pragma unroll
        for (int kk = 0; kk < 4; ++kk)
            #pragma unroll
            for (int mt = 0; mt < 8; ++mt)
                acc[mt] = __builtin_amdgcn_mfma_f32_16x16x32_fp8_fp8(
                    __builtin_bit_cast(long, W1s[mt * 256 + kk * 64 + lane]),
                    __builtin_bit_cast(long, ef[kk]), acc[mt], 0, 0, 0);

        // ---- silu -> fp8 -> Hs (frag-major writer algebra, validated R12) ----
        #pragma unroll
        for (int mt = 0; mt < 8; ++mt) {
            int lnp = (((mt & 1) << 1) | (lg >> 1)) * 16 + lrow;
            u32 pw = pk4fp8(fsilu(acc[mt][0]), fsilu(acc[mt][1]),
                            fsilu(acc[mt][2]), fsilu(acc[mt][3]));
            ((u32*)&HsW[(mt >> 1) * 64 + lnp])[lg & 1] = pw;
        }

        // ---- layer 2: C2[f][e], acc init = b2 (same-wave Hs b64 reads) ----
        f32x4 acc2[8];
        #pragma unroll
        for (int mt = 0; mt < 8; ++mt)
            acc2[mt] = *(const f32x4*)&b2s[mt * 16 + lg * 4];
        #pragma unroll
        for (int kk = 0; kk < 4; ++kk) {
            long hf = __builtin_bit_cast(long, HsW[kk * 64 + lane]);
            #pragma unroll
            for (int mt = 0; mt < 8; ++mt)
                acc2[mt] = __builtin_amdgcn_mfma_f32_16x16x32_fp8_fp8(
                    __builtin_bit_cast(long, W2s[mt * 256 + kk * 64 + lane]),
                    hf, acc2[mt], 0, 0, 0);
        }

        // ---- z = wo . silu(acc2): per-lane partial, reduce over lane-groups ----
        float zp = 0.f;
        #pragma unroll
        for (int mt = 0; mt < 8; ++mt) {
            f32x4 w4 = *(const f32x4*)&wos[mt * 16 + lg * 4];
            zp += w4[0] * fsilu(acc2[mt][0]) + w4[1] * fsilu(acc2[mt][1])
                + w4[2] * fsilu(acc2[mt][2]) + w4[3] * fsilu(acc2[mt][3]);
        }
        zp += __shfl_xor(zp, 16);
        zp += __shfl_xor(zp, 32);

        // ---- scatter: 16 lanes, atomicMax packed (fire-and-forget) ----
        if (lane < 16) {
            float z = zp + bo;
            int qz = (int)((z + 40.0f) * 256.0f + 0.5f);
            qz = qz < 0 ? 0 : (qz > 16383 ? 16383 : qz);
            u32 packed = 0xE0000000u | ((u32)(ei0 + lane + 1) << 14) | (u32)qz;
            atomicMax(&out[(size_t)b * NN + (size_t)i0 * N + (size_t)j0], packed);
        }
    }
}

extern "C" void kernel_launch(void* const* d_in, const int* in_sizes, int n_in,
                              void* d_out, int out_size, void* d_ws, size_t ws_size,
                              hipStream_t stream) {
    const float* edge_attr  = (const float*)d_in[0];
    const int*   edge_index = (const int*)d_in[1];
    const float* W1   = (const float*)d_in[2];
    const float* b1   = (const float*)d_in[3];
    const float* W2   = (const float*)d_in[4];
    const float* b2   = (const float*)d_in[5];
    const float* Wout = (const float*)d_in[6];
    const float* bout = (const float*)d_in[7];

    long rows = (long)in_sizes[0] / DD;        // B*E = 1,024,000
    int  E    = in_sizes[1] / 64;              // 32000 (B=32)
    int  nWT  = (int)(rows / 16);              // 64000 wave-tiles
    int  Bb   = (int)(rows / E);               // 32
    int  N    = (int)(sqrtf((float)(out_size / Bb)) + 0.5f);   // 1000

    u32* outp = (u32*)d_out;
    long n4 = (long)out_size >> 2;

    float fv = logf(1e-10f);
    u32 LE; memcpy(&LE, &fv, 4);               // log(1e-10) bits, < 0xE0000000

    const int SMEM = 67072;                    // 16K+16K+1.5K+32K + pad
    hipFuncSetAttribute((const void*)mlp_scatter,
                        hipFuncAttributeMaxDynamicSharedMemorySize, SMEM);

    mlp_scatter<<<256, 1024, SMEM, stream>>>(edge_attr, edge_index, W1, b1, W2, b2,
                                             Wout, bout, outp, E, nWT, N);
    decode_sparse<<<2048, 256, 0, stream>>>(outp, n4, LE);
}